// Round 1
// baseline (238.801 us; speedup 1.0000x reference)
//
#include <hip/hip_runtime.h>
#include <math.h>

#define D 4096
#define NT 256
#define PER 16           // D / NT
#define EPS 1e-5f
#define EPS_SQRT 3.16227766016837933e-3f
#define LN2 0.69314718055994531f
#define NBLOCKS 2048

__global__ __launch_bounds__(NT) void lnn_kernel(const float* __restrict__ x,
                                                 const float* __restrict__ w,
                                                 const float* __restrict__ b,
                                                 float* __restrict__ out,
                                                 int rows, int rpb) {
    const int tid = threadIdx.x;
    const int wave = tid >> 6;
    const int r0 = blockIdx.x * rpb;
    int r1 = r0 + rpb; if (r1 > rows) r1 = rows;
    if (r0 >= r1) return;

    __shared__ float red1[4][2];   // pass-1 partials (mean/var)
    __shared__ float red2[4][5];   // pass-2 partials (5 sums) -- separate buffer: saves a barrier

    const float inv_d = 1.f / (float)D;

    // ---- load first row: 16 floats/thread as 4x float4, coalesced ----
    float v[PER];
    {
        const float4* x4 = (const float4*)(x + (size_t)r0 * D);
#pragma unroll
        for (int c = 0; c < 4; ++c) {
            float4 f = x4[c * NT + tid];
            v[c*4+0] = f.x; v[c*4+1] = f.y; v[c*4+2] = f.z; v[c*4+3] = f.w;
        }
    }

    for (int r = r0; r < r1; ++r) {
        // ---- software prefetch of next row: issued NOW, consumed at loop end ----
        const bool pn = (r + 1 < r1);
        float n[PER];
        if (pn) {
            const float4* nx4 = (const float4*)(x + (size_t)(r + 1) * D);
#pragma unroll
            for (int c = 0; c < 4; ++c) {
                float4 f = nx4[c * NT + tid];
                n[c*4+0] = f.x; n[c*4+1] = f.y; n[c*4+2] = f.z; n[c*4+3] = f.w;
            }
        }

        // ---- pass 1: mean / var ----
        float s = 0.f, s2 = 0.f;
#pragma unroll
        for (int i = 0; i < PER; ++i) { s += v[i]; s2 = fmaf(v[i], v[i], s2); }
#pragma unroll
        for (int o = 32; o > 0; o >>= 1) {
            s  += __shfl_down(s,  o, 64);
            s2 += __shfl_down(s2, o, 64);
        }
        if ((tid & 63) == 0) { red1[wave][0] = s; red1[wave][1] = s2; }
        __syncthreads();
        s  = red1[0][0] + red1[1][0] + red1[2][0] + red1[3][0];
        s2 = red1[0][1] + red1[1][1] + red1[2][1] + red1[3][1];
        const float mean = s * inv_d;
        const float var  = s2 * inv_d - mean * mean;
        const float rstd = rsqrtf(var + EPS);
        const float nm   = -mean * rstd;

        // ---- pass 2: xs, L2 = log2(1+|xs|), 5 row-sums, store copysign(L2,xs) ----
        float s1 = 0.f, sxd = 0.f, sd = 0.f, sd2 = 0.f, sxd2 = 0.f;
#pragma unroll
        for (int i = 0; i < PER; ++i) {
            float xs   = fmaf(v[i], rstd, nm);
            float ab   = fabsf(xs);
            float onea = 1.f + ab;
            float L2   = __builtin_amdgcn_logf(onea);   // v_log_f32: log2(1+|xs|)
            float sv   = copysignf(L2, xs);
            v[i] = sv;                                   // all pass-3 needs: sign + L2
            s1 += sv;                                    // sum sign*L2 (scale by LN2 later)
            float l  = L2 * LN2;                         // natural log1p
            float dd = fmaf(onea, l, -ab);               // d = (1+|xs|)l1p - |xs|
            sxd = fmaf(xs, dd, sxd);
            sd += dd;
            sd2 = fmaf(dd, dd, sd2);
            float p1 = fmaf(onea, l * l, -(dd + dd));    // (1+|xs|)l1p^2 - 2d
            sxd2 = fmaf(ab, p1, sxd2);                   // xs*d2 = |xs|*p1
        }

        // ---- w/b loads: latency hides under the reduce + barrier + row scalars ----
        float4 wfs[4], bfs[4];
        {
            const float4* w4 = (const float4*)w;
            const float4* b4 = (const float4*)b;
#pragma unroll
            for (int c = 0; c < 4; ++c) {
                wfs[c] = w4[c * NT + tid];
                bfs[c] = b4[c * NT + tid];
            }
        }

#pragma unroll
        for (int o = 32; o > 0; o >>= 1) {
            s1   += __shfl_down(s1,   o, 64);
            sxd  += __shfl_down(sxd,  o, 64);
            sd   += __shfl_down(sd,   o, 64);
            sd2  += __shfl_down(sd2,  o, 64);
            sxd2 += __shfl_down(sxd2, o, 64);
        }
        if ((tid & 63) == 0) {
            red2[wave][0] = s1; red2[wave][1] = sxd; red2[wave][2] = sd;
            red2[wave][3] = sd2; red2[wave][4] = sxd2;
        }
        __syncthreads();
        s1   = red2[0][0] + red2[1][0] + red2[2][0] + red2[3][0];
        sxd  = red2[0][1] + red2[1][1] + red2[2][1] + red2[3][1];
        sd   = red2[0][2] + red2[1][2] + red2[2][2] + red2[3][2];
        sd2  = red2[0][3] + red2[1][3] + red2[2][3] + red2[3][3];
        sxd2 = red2[0][4] + red2[1][4] + red2[2][4] + red2[3][4];

        // ---- row scalars (redundant per thread, negligible) ----
        const float s1m   = s1 * (inv_d * LN2);
        const float dvar  = 2.f * sxd * inv_d;
        const float g1    = 0.5f * dvar - s1m;
        const float dmean = sd * inv_d;
        const float vard  = sd2 * inv_d - dmean * dmean;
        const float d2var = 2.f * (sxd2 * inv_d + vard);
        const float g2    = -0.5f * dvar * dvar + 0.5f * d2var;
        const float lm    = 1.f - g1 * __builtin_amdgcn_rcpf(g2 + EPS_SQRT);

        const float eta_p = lm;
        const float eta_n = 2.f - lm;
        const float ep = eta_p + ((eta_p >= 0.f) ? EPS_SQRT : -EPS_SQRT);
        const float en = eta_n + ((eta_n >= 0.f) ? EPS_SQRT : -EPS_SQRT);
        const bool  mp = fabsf(eta_p) <= EPS_SQRT;
        const bool  mn = fabsf(eta_n) <= EPS_SQRT;
        const float rp =  __builtin_amdgcn_rcpf(ep);
        const float rn = -__builtin_amdgcn_rcpf(en);

        float* orow = out + (size_t)r * D;

        if (!(mp || mn)) {
            // fast path (overwhelmingly common): no tr2/mask selects needed
#pragma unroll
            for (int c = 0; c < 4; ++c) {
                float wa[4] = {wfs[c].x, wfs[c].y, wfs[c].z, wfs[c].w};
                float ba[4] = {bfs[c].x, bfs[c].y, bfs[c].z, bfs[c].w};
                float oa[4];
#pragma unroll
                for (int j = 0; j < 4; ++j) {
                    float sv = v[c*4 + j];
                    bool pos = (sv >= 0.f);
                    float L2 = fabsf(sv);
                    float e  = pos ? ep : en;
                    float re = pos ? rp : rn;
                    // tr1 = re*(exp2(e*L2)-1) = fma(re, exp2, -re)
                    float tr = fmaf(re, __builtin_amdgcn_exp2f(e * L2), -re);
                    oa[j] = fmaf(tr, wa[j], ba[j]);
                }
                float4 o = {oa[0], oa[1], oa[2], oa[3]};
                ((float4*)orow)[c * NT + tid] = o;
            }
        } else {
            // general path with small-|eta| fallback
#pragma unroll
            for (int c = 0; c < 4; ++c) {
                float wa[4] = {wfs[c].x, wfs[c].y, wfs[c].z, wfs[c].w};
                float ba[4] = {bfs[c].x, bfs[c].y, bfs[c].z, bfs[c].w};
                float oa[4];
#pragma unroll
                for (int j = 0; j < 4; ++j) {
                    float sv = v[c*4 + j];
                    bool pos = (sv >= 0.f);
                    float L2 = fabsf(sv);
                    float e  = pos ? ep : en;
                    float re = pos ? rp : rn;
                    bool  m  = pos ? mp : mn;
                    float tr1 = fmaf(re, __builtin_amdgcn_exp2f(e * L2), -re);
                    float tr2 = sv * LN2;            // sign * l1p
                    float tr  = m ? tr2 : tr1;
                    oa[j] = fmaf(tr, wa[j], ba[j]);
                }
                float4 o = {oa[0], oa[1], oa[2], oa[3]};
                ((float4*)orow)[c * NT + tid] = o;
            }
        }

        // ---- rotate prefetched row into place ----
        if (pn) {
#pragma unroll
            for (int i = 0; i < PER; ++i) v[i] = n[i];
        }
    }
}

extern "C" void kernel_launch(void* const* d_in, const int* in_sizes, int n_in,
                              void* d_out, int out_size, void* d_ws, size_t ws_size,
                              hipStream_t stream) {
    const float* x = (const float*)d_in[0];
    const float* w = (const float*)d_in[1];
    const float* b = (const float*)d_in[2];
    float* out = (float*)d_out;
    const int rows = in_sizes[0] / D;   // 8192
    int nblocks = NBLOCKS;
    if (nblocks > rows) nblocks = rows;
    const int rpb = (rows + nblocks - 1) / nblocks;
    lnn_kernel<<<dim3(nblocks), dim3(NT), 0, stream>>>(x, w, b, out, rows, rpb);
}